// Round 1
// baseline (150.083 us; speedup 1.0000x reference)
//
#include <hip/hip_runtime.h>
#include <math.h>

#define W 131072
#define NJ 21
#define NB 20
#define TILE 256
#define FR 63  // floats per pose3d frame (3*21)

__global__ void zero_kernel(float* out) { out[0] = 0.0f; }

__global__ __launch_bounds__(TILE) void pose3d_loss_kernel(
    const float* __restrict__ pose3d,
    const float* __restrict__ cam,
    const float* __restrict__ p2d,
    const float* __restrict__ blen,
    const float* __restrict__ ldir,
    const int* __restrict__ bcon,
    const int* __restrict__ lcon,
    float* __restrict__ out)
{
  __shared__ float sP[(TILE + 2) * FR];   // 258 frames * 63 floats = 65016 B
  __shared__ float sBlen[NB];
  __shared__ int sBC[NB], sBP[NB], sLC[NB], sLP[NB];
  __shared__ float sWave[TILE / 64];

  const int tid = threadIdx.x;
  const int blk = blockIdx.x;
  const int f0 = blk * TILE;

  // ---- stage pose3d tile [f0, f0+TILE+2) into LDS, coalesced ----
  {
    const float* src = pose3d + (size_t)f0 * FR;
    const int limit = (W + 1) * FR - f0 * FR;  // floats actually available
    const int total = (TILE + 2) * FR;
    for (int i = tid; i < total; i += TILE)
      sP[i] = (i < limit) ? src[i] : 0.0f;
  }
  if (tid < NB) {
    sBlen[tid] = blen[tid];
    sBC[tid] = bcon[2 * tid];
    sBP[tid] = bcon[2 * tid + 1];
    sLC[tid] = lcon[2 * tid];
    sLP[tid] = lcon[2 * tid + 1];
  }
  __syncthreads();

  const int w = f0 + tid;                 // loss index, 0..W-1
  const float* P0 = sP + tid * FR;        // frame w
  const float* P1 = P0 + FR;              // frame w+1
  const float* P2 = P1 + FR;              // frame w+2

  // frame w+1 into registers (statically indexed uses only: proj + smooth)
  float p1f[FR];
#pragma unroll
  for (int i = 0; i < FR; ++i) p1f[i] = P1[i];

  float acc_proj = 0.f, acc_bone = 0.f, acc_smooth = 0.f, acc_lift = 0.f;

  // ---- projection loss ----
  {
    const float2* camv = (const float2*)(cam + (size_t)w * 6);
    float2 c0 = camv[0], c1 = camv[1], c2 = camv[2];
    float cr[2][3] = {{c0.x, c0.y, c1.x}, {c1.y, c2.x, c2.y}};
    const float2* pv = (const float2*)(p2d + (size_t)w * 42);
#pragma unroll
    for (int k = 0; k < 21; ++k) {
      float2 v = pv[k];
      {
        const int idx = 2 * k, i = idx / 21, j = idx % 21;
        float pr = cr[i][0] * p1f[j] + cr[i][1] * p1f[21 + j] + cr[i][2] * p1f[42 + j];
        float d = pr - v.x;
        acc_proj += d * d;
      }
      {
        const int idx = 2 * k + 1, i = idx / 21, j = idx % 21;
        float pr = cr[i][0] * p1f[j] + cr[i][1] * p1f[21 + j] + cr[i][2] * p1f[42 + j];
        float d = pr - v.y;
        acc_proj += d * d;
      }
    }
  }

  // ---- bone length loss: frame w for every thread; thread w==W-1 adds frame W ----
  {
#pragma unroll
    for (int bb = 0; bb < NB; ++bb) {
      int ci = sBC[bb], pi = sBP[bb];
      float dx = P0[ci] - P0[pi];
      float dy = P0[21 + ci] - P0[21 + pi];
      float dz = P0[42 + ci] - P0[42 + pi];
      float L = dx * dx + dy * dy + dz * dz;
      float t = L - sBlen[bb];
      acc_bone += t * t;
    }
    if (w == W - 1) {
#pragma unroll
      for (int bb = 0; bb < NB; ++bb) {
        int ci = sBC[bb], pi = sBP[bb];
        float dx = P1[ci] - P1[pi];
        float dy = P1[21 + ci] - P1[21 + pi];
        float dz = P1[42 + ci] - P1[42 + pi];
        float L = dx * dx + dy * dy + dz * dz;
        float t = L - sBlen[bb];
        acc_bone += t * t;
      }
    }
  }

  // ---- smoothness (second difference), valid for w <= W-2 ----
  if (w < W - 1) {
#pragma unroll
    for (int i = 0; i < FR; ++i) {
      float d2 = P2[i] - 2.0f * p1f[i] + P0[i];
      acc_smooth += d2 * d2;
    }
  }

  // ---- lift direction loss ----
  {
    const float4* lv = (const float4*)(ldir + (size_t)w * 60);
    float ld[60];
#pragma unroll
    for (int k = 0; k < 15; ++k) {
      float4 v = lv[k];
      ld[4 * k]     = v.x;
      ld[4 * k + 1] = v.y;
      ld[4 * k + 2] = v.z;
      ld[4 * k + 3] = v.w;
    }
#pragma unroll
    for (int bb = 0; bb < NB; ++bb) {
      int ci = sLC[bb], pi = sLP[bb];
      float bx = P1[ci] - P1[pi];
      float by = P1[21 + ci] - P1[21 + pi];
      float bz = P1[42 + ci] - P1[42 + pi];
      float inv = 1.0f / sqrtf(bx * bx + by * by + bz * bz);
      float ex = ld[bb]      - bx * inv;
      float ey = ld[20 + bb] - by * inv;
      float ez = ld[40 + bb] - bz * inv;
      acc_lift += ex * ex + ey * ey + ez * ez;
    }
  }

  // ---- weighted combine + reduction ----
  float s = acc_proj * (1.0f / 42.0f) + acc_bone * (1.0f / 20.0f)
          + acc_smooth * (0.5f / 63.0f) + acc_lift * (0.1f / 63.0f);

#pragma unroll
  for (int off = 32; off > 0; off >>= 1) s += __shfl_down(s, off, 64);
  if ((tid & 63) == 0) sWave[tid >> 6] = s;
  __syncthreads();
  if (tid == 0) {
    float tot = 0.f;
#pragma unroll
    for (int i = 0; i < TILE / 64; ++i) tot += sWave[i];
    atomicAdd(out, tot);
  }
}

extern "C" void kernel_launch(void* const* d_in, const int* in_sizes, int n_in,
                              void* d_out, int out_size, void* d_ws, size_t ws_size,
                              hipStream_t stream) {
  const float* pose3d = (const float*)d_in[0];
  const float* cam    = (const float*)d_in[1];
  const float* p2d    = (const float*)d_in[2];
  const float* blen   = (const float*)d_in[3];
  const float* ldir   = (const float*)d_in[4];
  const int*   bcon   = (const int*)d_in[5];
  const int*   lcon   = (const int*)d_in[6];
  float* out = (float*)d_out;

  zero_kernel<<<1, 1, 0, stream>>>(out);
  pose3d_loss_kernel<<<W / TILE, TILE, 0, stream>>>(
      pose3d, cam, p2d, blen, ldir, bcon, lcon, out);
}